// Round 5
// baseline (30693.979 us; speedup 1.0000x reference)
//
#include <hip/hip_runtime.h>
#include <stdint.h>

#define H4T 2048
#define BATCHN 32
#define TSTEPS 1000
#define NBLK 256
#define NTHR 512
#define NSLICE 16   // i-slices == jl groups (NTHR = 32 * NSLICE)

// ws layout:
//   [0, 256K)            : h buffer 0  (interleaved [i/4][b][4] floats)
//   [256K, 512K)         : h buffer 1
//   [512K, 512K+4K)      : go flags,   1000 x u32 (padded to 1024)
//   [512K+4K, +1000K)    : arrival flags, 1000 steps x 256 blocks x u32

__device__ __forceinline__ float ht_clip(float w) {
  return fminf(fmaxf(w, 1e-15f), 1.0f);
}

// W_rec[j, i] for j = g*512 + jj. Block-sparse per reference.
__device__ float wval(int g, int jj, int i,
                      const float* s2s_f, const float* t2s, const float* a2s,
                      const float* s2n, const float* n2t,
                      const float* t2a, const float* a2a) {
  int ig = i >> 9;
  int ii = i & 511;
  float v = 0.0f;
  if (g == 0) {
    if (ig == 0)      v = -s2s_f[jj * 512 + ii];                                  // -(str2str_fixed)
    else if (ig == 2) v = (jj >= 256) ? ht_clip(t2s[jj * 512 + ii]) : 0.0f;       // thal2str row-masked
    else if (ig == 3) v = (ii < 359) ? ht_clip(a2s[jj * 512 + ii]) : 0.0f;        // alm2str col-masked
  } else if (g == 1) {
    if (ig == 0)      v = -ht_clip(s2n[jj * 512 + ii]);                           // -str2snr
  } else if (g == 2) {
    if (ig == 1)      v = -ht_clip(n2t[jj * 512 + ii]);                           // -snr2thal
  } else {
    if (ig == 2)      v = ht_clip(t2a[jj * 512 + ii]);                            // thal2alm
    else if (ig == 3) v = ht_clip(a2a[jj * 512 + ii]) * ((ii < 359) ? 1.0f : -1.0f); // alm2alm * d_alm
  }
  return v;
}

__global__ void prep_h0(const float* __restrict__ hn, float* __restrict__ hbuf0) {
  int e = blockIdx.x * blockDim.x + threadIdx.x;
  if (e < BATCHN * H4T) {
    int b = e >> 11;
    int j = e & 2047;
    hbuf0[(j >> 2) * 128 + (b << 2) + (j & 3)] = hn[e];
  }
}

template<int NCOLS, int IEXT, bool SPLIT, int LOG2NC>
__device__ __forceinline__ void run_group(
    int g, int j0, int ibase4, float tonicv,
    const float* __restrict__ inp, const float* __restrict__ inhib,
    const float* s2s_f, const float* t2s, const float* a2s,
    const float* s2n, const float* n2t, const float* t2a, const float* a2a,
    const float* __restrict__ inpw,
    float* __restrict__ out_hn, float* __restrict__ out_rnn,
    float* hbuf0, float* hbuf1,
    unsigned int* __restrict__ go, unsigned int* __restrict__ arr,
    float* Wl, float* red, float* iwl)
{
  const int tid = threadIdx.x;
  const int bid = blockIdx.x;
  const int b   = tid & 31;     // batch lane
  const int jl  = tid >> 5;     // i-slice id (0..15)
  constexpr int IEXT4  = IEXT / 4;
  constexpr int SLICE4 = IEXT4 / NSLICE;

  // ---- one-time: build this block's W slice in LDS (persistent all steps) ----
  for (int idx = tid; idx < NCOLS * IEXT; idx += NTHR) {
    int c  = idx / IEXT;
    int fi = idx - c * IEXT;
    int i  = SPLIT ? ((fi < 512) ? fi : fi + 512) : ibase4 * 4 + fi;
    Wl[c * IEXT + fi] = wval(g, (j0 + c) & 511, i, s2s_f, t2s, a2s, s2n, n2t, t2a, a2a);
  }
  if (tid < NCOLS) {
    int j = j0 + tid;
    iwl[tid] = (j >= 256 && j < 512) ? ht_clip(inpw[j]) : 0.0f;
  }
  __syncthreads();

  int cur = 0;
  const float4* __restrict__ Wl4 = (const float4*)Wl;

  for (int t = 0; t < TSTEPS; ++t) {
    const float* hb  = cur ? hbuf1 : hbuf0;
    float*       hbn = cur ? hbuf0 : hbuf1;
    const float4* __restrict__ hb4 = (const float4*)hb;

    // ---- i-loop: W broadcast from LDS, h coalesced from global (cached) ----
    float acc[NCOLS];
#pragma unroll
    for (int c = 0; c < NCOLS; ++c) acc[c] = 0.0f;

    for (int it = 0; it < SLICE4; ++it) {
      int fi4 = jl * SLICE4 + it;
      int i4  = ibase4 + (SPLIT ? ((fi4 >= 128) ? fi4 + 128 : fi4) : fi4);
      float4 hv = hb4[i4 * 32 + b];
#pragma unroll
      for (int c = 0; c < NCOLS; ++c) {
        float4 wv = Wl4[c * IEXT4 + fi4];
        acc[c] = fmaf(hv.x, wv.x, acc[c]);
        acc[c] = fmaf(hv.y, wv.y, acc[c]);
        acc[c] = fmaf(hv.z, wv.z, acc[c]);
        acc[c] = fmaf(hv.w, wv.w, acc[c]);
      }
    }

    // ---- write partials: red[jl][c][b], b consecutive -> conflict-free ----
#pragma unroll
    for (int c = 0; c < NCOLS; ++c)
      red[(jl * NCOLS + c) * 33 + b] = acc[c];
    __syncthreads();

    // ---- reduce + pointwise update + stores, one phase ----
    if (tid < 32 * NCOLS) {
      int c  = tid & (NCOLS - 1);
      int pb = tid >> LOG2NC;
      float s = 0.0f;
#pragma unroll
      for (int sl = 0; sl < NSLICE; ++sl)
        s += red[(sl * NCOLS + c) * 33 + pb];
      int j = j0 + c;
      float hold = hb[(j >> 2) * 128 + (pb << 2) + (j & 3)];
      float inh  = inhib[(size_t)pb * (TSTEPS * H4T) + (size_t)t * H4T + j];
      float iv   = inp[pb * TSTEPS + t];
      float d    = inh + tonicv + iv * iwl[c];
      float hnew = fmaxf(0.0f, fmaf(0.01f, s + d - hold, hold));
      // device-scope store: lands MALL-visible, nothing dirty in local L2
      __hip_atomic_store(&hbn[(j >> 2) * 128 + (pb << 2) + (j & 3)], hnew,
                         __ATOMIC_RELAXED, __HIP_MEMORY_SCOPE_AGENT);
      out_rnn[(size_t)pb * (TSTEPS * H4T) + (size_t)t * H4T + j] = hnew;
      if (t == TSTEPS - 1) out_hn[pb * H4T + j] = hnew;
    }
    __syncthreads();   // drains all waves' vmcnt -> h stores are MALL-visible

    // ---- contention-free device barrier ----
    if (tid == 0)
      __hip_atomic_store(&arr[t * NBLK + bid], 1u,
                         __ATOMIC_RELEASE, __HIP_MEMORY_SCOPE_AGENT);
    if (bid == 0) {
      // checker: 512 threads poll the 256 arrival flags in parallel
      int ok;
      do {
        ok = (tid < NBLK)
               ? (__hip_atomic_load(&arr[t * NBLK + tid],
                                    __ATOMIC_RELAXED, __HIP_MEMORY_SCOPE_AGENT) != 0u)
               : 1;
        if (!ok) __builtin_amdgcn_s_sleep(1);
      } while (!__syncthreads_and(ok));
      if (tid == 0)
        __hip_atomic_store(&go[t], 1u, __ATOMIC_RELEASE, __HIP_MEMORY_SCOPE_AGENT);
    } else {
      if (tid == 0) {
        while (__hip_atomic_load(&go[t], __ATOMIC_RELAXED,
                                 __HIP_MEMORY_SCOPE_AGENT) == 0u)
          __builtin_amdgcn_s_sleep(2);
      }
      __syncthreads();
    }
    __builtin_amdgcn_fence(__ATOMIC_ACQUIRE, "agent");  // L1/L2 inv -> fresh h
    cur ^= 1;
  }
}

__global__ __launch_bounds__(NTHR) void rnn_persistent(
    const float* __restrict__ inp, const float* __restrict__ inhib,
    const float* s2s_f, const float* t2s, const float* a2s,
    const float* s2n, const float* n2t, const float* t2a, const float* a2a,
    const float* __restrict__ inpw,
    float* __restrict__ out_hn, float* __restrict__ out_rnn,
    float* hbuf0, float* hbuf1, unsigned int* go, unsigned int* arr)
{
  __shared__ __align__(16) float Wl[8192];    // W slice, persistent across steps
  __shared__ float red[8448];                 // [NSLICE][NCOLS][33] partials
  __shared__ float iwl[16];

  int bid = blockIdx.x;
  if (bid < 128) {
    run_group<4, 1536, true, 2>(0, bid * 4, 0, 0.0f,
        inp, inhib, s2s_f, t2s, a2s, s2n, n2t, t2a, a2a, inpw,
        out_hn, out_rnn, hbuf0, hbuf1, go, arr, Wl, red, iwl);
  } else if (bid < 160) {
    run_group<16, 512, false, 4>(1, 512 + (bid - 128) * 16, 0, 0.7f,
        inp, inhib, s2s_f, t2s, a2s, s2n, n2t, t2a, a2a, inpw,
        out_hn, out_rnn, hbuf0, hbuf1, go, arr, Wl, red, iwl);
  } else if (bid < 192) {
    run_group<16, 512, false, 4>(2, 1024 + (bid - 160) * 16, 128, 1.0f,
        inp, inhib, s2s_f, t2s, a2s, s2n, n2t, t2a, a2a, inpw,
        out_hn, out_rnn, hbuf0, hbuf1, go, arr, Wl, red, iwl);
  } else {
    run_group<8, 1024, false, 3>(3, 1536 + (bid - 192) * 8, 256, 0.0f,
        inp, inhib, s2s_f, t2s, a2s, s2n, n2t, t2a, a2a, inpw,
        out_hn, out_rnn, hbuf0, hbuf1, go, arr, Wl, red, iwl);
  }
}

extern "C" void kernel_launch(void* const* d_in, const int* in_sizes, int n_in,
                              void* d_out, int out_size, void* d_ws, size_t ws_size,
                              hipStream_t stream) {
  const float* inp   = (const float*)d_in[0];   // [32,1000,1]
  const float* hn    = (const float*)d_in[1];   // [1,32,2048]
  const float* inhib = (const float*)d_in[2];   // [32,1000,2048]
  // d_in[3] = str2str_w (multiplied by 0.0 in reference -> unused)
  const float* t2a   = (const float*)d_in[4];   // thal2alm_w
  const float* t2s   = (const float*)d_in[5];   // thal2str_w
  const float* a2a   = (const float*)d_in[6];   // alm2alm_w
  const float* a2s   = (const float*)d_in[7];   // alm2str_w
  const float* s2n   = (const float*)d_in[8];   // str2snr_w
  const float* n2t   = (const float*)d_in[9];   // snr2thal_w
  const float* inpw  = (const float*)d_in[10];  // inp_weight [1,2048]
  const float* s2s_f = (const float*)d_in[11];  // str2str_fixed

  float* out_hn  = (float*)d_out;               // [1,32,2048]
  float* out_rnn = out_hn + BATCHN * H4T;       // [32,1000,2048]

  float* hbuf0 = (float*)d_ws;
  float* hbuf1 = hbuf0 + BATCHN * H4T;
  unsigned int* go  = (unsigned int*)((char*)d_ws + 512 * 1024);
  unsigned int* arr = go + 1024;

  // zero go (4KB) + arrival flags (1000*256*4 = 1MB), once per call
  hipMemsetAsync(go, 0, 4096 + TSTEPS * NBLK * sizeof(unsigned int), stream);
  prep_h0<<<256, 256, 0, stream>>>(hn, hbuf0);
  rnn_persistent<<<NBLK, NTHR, 0, stream>>>(
      inp, inhib, s2s_f, t2s, a2s, s2n, n2t, t2a, a2a, inpw,
      out_hn, out_rnn, hbuf0, hbuf1, go, arr);
}

// Round 6
// 10026.966 us; speedup vs baseline: 3.0611x; 3.0611x over previous
//
#include <hip/hip_runtime.h>
#include <stdint.h>

#define H4T 2048
#define BATCHN 32
#define TSTEPS 1000
#define NBLK 256
#define NTHR 512
#define NSLICE 16   // i-slices == jl groups (NTHR = 32 * NSLICE)

// ws layout:
//   [0, 256K)            : h buffer 0  (interleaved [i/4][b][4] floats)
//   [256K, 512K)         : h buffer 1
//   [512K, 512K+1M)      : arrival flags, 1000 steps x 256 blocks x u32

__device__ __forceinline__ float ht_clip(float w) {
  return fminf(fmaxf(w, 1e-15f), 1.0f);
}

// W_rec[j, i] for j = g*512 + jj. Block-sparse per reference.
__device__ float wval(int g, int jj, int i,
                      const float* s2s_f, const float* t2s, const float* a2s,
                      const float* s2n, const float* n2t,
                      const float* t2a, const float* a2a) {
  int ig = i >> 9;
  int ii = i & 511;
  float v = 0.0f;
  if (g == 0) {
    if (ig == 0)      v = -s2s_f[jj * 512 + ii];                                  // -(str2str_fixed)
    else if (ig == 2) v = (jj >= 256) ? ht_clip(t2s[jj * 512 + ii]) : 0.0f;       // thal2str row-masked
    else if (ig == 3) v = (ii < 359) ? ht_clip(a2s[jj * 512 + ii]) : 0.0f;        // alm2str col-masked
  } else if (g == 1) {
    if (ig == 0)      v = -ht_clip(s2n[jj * 512 + ii]);                           // -str2snr
  } else if (g == 2) {
    if (ig == 1)      v = -ht_clip(n2t[jj * 512 + ii]);                           // -snr2thal
  } else {
    if (ig == 2)      v = ht_clip(t2a[jj * 512 + ii]);                            // thal2alm
    else if (ig == 3) v = ht_clip(a2a[jj * 512 + ii]) * ((ii < 359) ? 1.0f : -1.0f); // alm2alm * d_alm
  }
  return v;
}

__global__ void prep_h0(const float* __restrict__ hn, float* __restrict__ hbuf0) {
  int e = blockIdx.x * blockDim.x + threadIdx.x;
  if (e < BATCHN * H4T) {
    int b = e >> 11;
    int j = e & 2047;
    hbuf0[(j >> 2) * 128 + (b << 2) + (j & 3)] = hn[e];
  }
}

template<int NCOLS, int IEXT, bool SPLIT, int LOG2NC>
__device__ __forceinline__ void run_group(
    int g, int j0, int ibase4, float tonicv,
    const float* __restrict__ inp, const float* __restrict__ inhib,
    const float* s2s_f, const float* t2s, const float* a2s,
    const float* s2n, const float* n2t, const float* t2a, const float* a2a,
    const float* __restrict__ inpw,
    float* __restrict__ out_hn, float* __restrict__ out_rnn,
    float* hbuf0, float* hbuf1, unsigned int* __restrict__ arr,
    float* Wl, float* red, float* iwl)
{
  const int tid = threadIdx.x;
  const int bid = blockIdx.x;
  const int b   = tid & 31;     // batch lane
  const int jl  = tid >> 5;     // i-slice id (0..15)
  constexpr int IEXT4  = IEXT / 4;
  constexpr int SLICE4 = IEXT4 / NSLICE;
  constexpr int CHUNK  = 8;     // float4-iters per load batch (latency amortize)
  static_assert(SLICE4 % CHUNK == 0, "slice not divisible by chunk");

  // ---- one-time: build this block's W slice in LDS (persistent all steps) ----
  for (int idx = tid; idx < NCOLS * IEXT; idx += NTHR) {
    int c  = idx / IEXT;
    int fi = idx - c * IEXT;
    int i  = SPLIT ? ((fi < 512) ? fi : fi + 512) : ibase4 * 4 + fi;
    Wl[c * IEXT + fi] = wval(g, (j0 + c) & 511, i, s2s_f, t2s, a2s, s2n, n2t, t2a, a2a);
  }
  if (tid < NCOLS) {
    int j = j0 + tid;
    iwl[tid] = (j >= 256 && j < 512) ? ht_clip(inpw[j]) : 0.0f;
  }

  // ---- hold (h_old at this thread's (c,pb)) lives in a register across steps ----
  float hold = 0.0f;
  if (tid < 32 * NCOLS) {
    int c  = tid & (NCOLS - 1);
    int pb = tid >> LOG2NC;
    int j  = j0 + c;
    hold = hbuf0[(j >> 2) * 128 + (pb << 2) + (j & 3)];
  }
  __syncthreads();

  int cur = 0;
  const float4* __restrict__ Wl4 = (const float4*)Wl;

  for (int t = 0; t < TSTEPS; ++t) {
    const float* hb  = cur ? hbuf1 : hbuf0;
    float*       hbn = cur ? hbuf0 : hbuf1;
    const unsigned long long* __restrict__ hb8 = (const unsigned long long*)hb;

    // ---- i-loop: h via sc1 loads (MALL-coherent, bypass L1/L2), W from LDS ----
    float acc[NCOLS];
#pragma unroll
    for (int c = 0; c < NCOLS; ++c) acc[c] = 0.0f;

    for (int ch = 0; ch < SLICE4 / CHUNK; ++ch) {
      unsigned long long p[CHUNK][2];
#pragma unroll
      for (int k = 0; k < CHUNK; ++k) {
        int fi4 = jl * SLICE4 + ch * CHUNK + k;
        int i4  = ibase4 + (SPLIT ? ((fi4 >= 128) ? fi4 + 128 : fi4) : fi4);
        const unsigned long long* hp = hb8 + (size_t)(i4 * 32 + b) * 2;
        p[k][0] = __hip_atomic_load(hp,     __ATOMIC_RELAXED, __HIP_MEMORY_SCOPE_AGENT);
        p[k][1] = __hip_atomic_load(hp + 1, __ATOMIC_RELAXED, __HIP_MEMORY_SCOPE_AGENT);
      }
#pragma unroll
      for (int k = 0; k < CHUNK; ++k) {
        int fi4 = jl * SLICE4 + ch * CHUNK + k;
        float2 f0 = __builtin_bit_cast(float2, p[k][0]);
        float2 f1 = __builtin_bit_cast(float2, p[k][1]);
#pragma unroll
        for (int c = 0; c < NCOLS; ++c) {
          float4 wv = Wl4[c * IEXT4 + fi4];
          acc[c] = fmaf(f0.x, wv.x, acc[c]);
          acc[c] = fmaf(f0.y, wv.y, acc[c]);
          acc[c] = fmaf(f1.x, wv.z, acc[c]);
          acc[c] = fmaf(f1.y, wv.w, acc[c]);
        }
      }
    }

    // ---- write partials: red[jl][c][b], b consecutive -> conflict-free ----
#pragma unroll
    for (int c = 0; c < NCOLS; ++c)
      red[(jl * NCOLS + c) * 33 + b] = acc[c];
    __syncthreads();

    // ---- reduce + pointwise update + stores ----
    if (tid < 32 * NCOLS) {
      int c  = tid & (NCOLS - 1);
      int pb = tid >> LOG2NC;
      float s = 0.0f;
#pragma unroll
      for (int sl = 0; sl < NSLICE; ++sl)
        s += red[(sl * NCOLS + c) * 33 + pb];
      int j = j0 + c;
      float inh  = inhib[(size_t)pb * (TSTEPS * H4T) + (size_t)t * H4T + j];
      float iv   = inp[pb * TSTEPS + t];
      float d    = inh + tonicv + iv * iwl[c];
      float hnew = fmaxf(0.0f, fmaf(0.01f, s + d - hold, hold));
      hold = hnew;
      // sc1 store: lands at MALL, nothing dirty in L2 for h
      __hip_atomic_store(&hbn[(j >> 2) * 128 + (pb << 2) + (j & 3)], hnew,
                         __ATOMIC_RELAXED, __HIP_MEMORY_SCOPE_AGENT);
      out_rnn[(size_t)pb * (TSTEPS * H4T) + (size_t)t * H4T + j] = hnew;
      if (t == TSTEPS - 1) out_hn[pb * H4T + j] = hnew;
    }
    __syncthreads();   // per-wave s_waitcnt vmcnt(0) before s_barrier: all h stores MALL-acked

    // ---- flat device barrier: relaxed sc1 flag store + parallel poll, NO fences ----
    if (tid == 0)
      __hip_atomic_store(&arr[t * NBLK + bid], 1u,
                         __ATOMIC_RELAXED, __HIP_MEMORY_SCOPE_AGENT);
    int ok;
    do {
      ok = (tid < NBLK)
             ? (__hip_atomic_load(&arr[t * NBLK + tid],
                                  __ATOMIC_RELAXED, __HIP_MEMORY_SCOPE_AGENT) != 0u)
             : 1;
      if (!ok) __builtin_amdgcn_s_sleep(1);
    } while (!__syncthreads_and(ok));

    cur ^= 1;
  }
}

__global__ __launch_bounds__(NTHR) void rnn_persistent(
    const float* __restrict__ inp, const float* __restrict__ inhib,
    const float* s2s_f, const float* t2s, const float* a2s,
    const float* s2n, const float* n2t, const float* t2a, const float* a2a,
    const float* __restrict__ inpw,
    float* __restrict__ out_hn, float* __restrict__ out_rnn,
    float* hbuf0, float* hbuf1, unsigned int* arr)
{
  __shared__ __align__(16) float Wl[8192];    // W slice, persistent across steps
  __shared__ float red[8448];                 // [NSLICE][NCOLS][33] partials
  __shared__ float iwl[16];

  int bid = blockIdx.x;
  if (bid < 128) {
    run_group<4, 1536, true, 2>(0, bid * 4, 0, 0.0f,
        inp, inhib, s2s_f, t2s, a2s, s2n, n2t, t2a, a2a, inpw,
        out_hn, out_rnn, hbuf0, hbuf1, arr, Wl, red, iwl);
  } else if (bid < 160) {
    run_group<16, 512, false, 4>(1, 512 + (bid - 128) * 16, 0, 0.7f,
        inp, inhib, s2s_f, t2s, a2s, s2n, n2t, t2a, a2a, inpw,
        out_hn, out_rnn, hbuf0, hbuf1, arr, Wl, red, iwl);
  } else if (bid < 192) {
    run_group<16, 512, false, 4>(2, 1024 + (bid - 160) * 16, 128, 1.0f,
        inp, inhib, s2s_f, t2s, a2s, s2n, n2t, t2a, a2a, inpw,
        out_hn, out_rnn, hbuf0, hbuf1, arr, Wl, red, iwl);
  } else {
    run_group<8, 1024, false, 3>(3, 1536 + (bid - 192) * 8, 256, 0.0f,
        inp, inhib, s2s_f, t2s, a2s, s2n, n2t, t2a, a2a, inpw,
        out_hn, out_rnn, hbuf0, hbuf1, arr, Wl, red, iwl);
  }
}

extern "C" void kernel_launch(void* const* d_in, const int* in_sizes, int n_in,
                              void* d_out, int out_size, void* d_ws, size_t ws_size,
                              hipStream_t stream) {
  const float* inp   = (const float*)d_in[0];   // [32,1000,1]
  const float* hn    = (const float*)d_in[1];   // [1,32,2048]
  const float* inhib = (const float*)d_in[2];   // [32,1000,2048]
  // d_in[3] = str2str_w (multiplied by 0.0 in reference -> unused)
  const float* t2a   = (const float*)d_in[4];   // thal2alm_w
  const float* t2s   = (const float*)d_in[5];   // thal2str_w
  const float* a2a   = (const float*)d_in[6];   // alm2alm_w
  const float* a2s   = (const float*)d_in[7];   // alm2str_w
  const float* s2n   = (const float*)d_in[8];   // str2snr_w
  const float* n2t   = (const float*)d_in[9];   // snr2thal_w
  const float* inpw  = (const float*)d_in[10];  // inp_weight [1,2048]
  const float* s2s_f = (const float*)d_in[11];  // str2str_fixed

  float* out_hn  = (float*)d_out;               // [1,32,2048]
  float* out_rnn = out_hn + BATCHN * H4T;       // [32,1000,2048]

  float* hbuf0 = (float*)d_ws;
  float* hbuf1 = hbuf0 + BATCHN * H4T;
  unsigned int* arr = (unsigned int*)((char*)d_ws + 512 * 1024);

  // zero arrival flags (1000*256*4 = 1MB), once per call
  hipMemsetAsync(arr, 0, TSTEPS * NBLK * sizeof(unsigned int), stream);
  prep_h0<<<256, 256, 0, stream>>>(hn, hbuf0);
  rnn_persistent<<<NBLK, NTHR, 0, stream>>>(
      inp, inhib, s2s_f, t2s, a2s, s2n, n2t, t2a, a2a, inpw,
      out_hn, out_rnn, hbuf0, hbuf1, arr);
}

// Round 7
// 9731.828 us; speedup vs baseline: 3.1540x; 1.0303x over previous
//
#include <hip/hip_runtime.h>
#include <stdint.h>

#define H4T 2048
#define BATCHN 32
#define TSTEPS 1000
#define NBLK 256
#define NTHR 512
#define NSLICE 16   // i-slices == jl groups (NTHR = 32 * NSLICE)

typedef float f2 __attribute__((ext_vector_type(2)));

// ws layout:
//   [0, 256K)            : h buffer 0  (interleaved [i/4][b][4] floats)
//   [256K, 512K)         : h buffer 1
//   [512K, 512K+1M)      : arrival flags, 1000 steps x 256 blocks x u32

__device__ __forceinline__ float ht_clip(float w) {
  return fminf(fmaxf(w, 1e-15f), 1.0f);
}

// W_rec[j, i] for j = g*512 + jj. Block-sparse per reference.
__device__ float wval(int g, int jj, int i,
                      const float* s2s_f, const float* t2s, const float* a2s,
                      const float* s2n, const float* n2t,
                      const float* t2a, const float* a2a) {
  int ig = i >> 9;
  int ii = i & 511;
  float v = 0.0f;
  if (g == 0) {
    if (ig == 0)      v = -s2s_f[jj * 512 + ii];                                  // -(str2str_fixed)
    else if (ig == 2) v = (jj >= 256) ? ht_clip(t2s[jj * 512 + ii]) : 0.0f;       // thal2str row-masked
    else if (ig == 3) v = (ii < 359) ? ht_clip(a2s[jj * 512 + ii]) : 0.0f;        // alm2str col-masked
  } else if (g == 1) {
    if (ig == 0)      v = -ht_clip(s2n[jj * 512 + ii]);                           // -str2snr
  } else if (g == 2) {
    if (ig == 1)      v = -ht_clip(n2t[jj * 512 + ii]);                           // -snr2thal
  } else {
    if (ig == 2)      v = ht_clip(t2a[jj * 512 + ii]);                            // thal2alm
    else if (ig == 3) v = ht_clip(a2a[jj * 512 + ii]) * ((ii < 359) ? 1.0f : -1.0f); // alm2alm * d_alm
  }
  return v;
}

__global__ void prep_h0(const float* __restrict__ hn, float* __restrict__ hbuf0) {
  int e = blockIdx.x * blockDim.x + threadIdx.x;
  if (e < BATCHN * H4T) {
    int b = e >> 11;
    int j = e & 2047;
    hbuf0[(j >> 2) * 128 + (b << 2) + (j & 3)] = hn[e];
  }
}

// MAP: 0 -> i = ibase4*4 + fi   (contiguous extent)
//      1 -> i = fi<512 ? fi : fi+512    ([0,512) U [1024,2048), E=1536)
//      2 -> i = fi<512 ? fi : fi+1024   ([0,512) U [1536,2048), E=1024)
template<int NCOLS, int IEXT, int MAP, int LOG2NC>
__device__ __forceinline__ void run_group(
    int g, int j0, int ibase4, float tonicv,
    const float* __restrict__ inp, const float* __restrict__ inhib,
    const float* s2s_f, const float* t2s, const float* a2s,
    const float* s2n, const float* n2t, const float* t2a, const float* a2a,
    const float* __restrict__ inpw,
    float* __restrict__ out_hn, float* __restrict__ out_rnn,
    float* hbuf0, float* hbuf1, unsigned int* __restrict__ arr,
    float* Wl, float* red, float* iwl)
{
  const int tid = threadIdx.x;
  const int bid = blockIdx.x;
  const int b   = tid & 31;     // batch lane
  const int jl  = tid >> 5;     // i-slice id (0..15)
  constexpr int IEXT4  = IEXT / 4;
  constexpr int SLICE4 = IEXT4 / NSLICE;

  // ---- one-time: build this block's W slice in LDS (persistent all steps) ----
  for (int idx = tid; idx < NCOLS * IEXT; idx += NTHR) {
    int c  = idx / IEXT;
    int fi = idx - c * IEXT;
    int i  = (MAP == 1) ? ((fi < 512) ? fi : fi + 512)
           : (MAP == 2) ? ((fi < 512) ? fi : fi + 1024)
                        : ibase4 * 4 + fi;
    Wl[c * IEXT + fi] = wval(g, (j0 + c) & 511, i, s2s_f, t2s, a2s, s2n, n2t, t2a, a2a);
  }
  if (tid < NCOLS) {
    int j = j0 + tid;
    iwl[tid] = (j >= 256 && j < 512) ? ht_clip(inpw[j]) : 0.0f;
  }

  // ---- per-thread state held in registers across all steps ----
  float hold = 0.0f, inh_r = 0.0f, iv_r = 0.0f;
  if (tid < 32 * NCOLS) {
    int c  = tid & (NCOLS - 1);
    int pb = tid >> LOG2NC;
    int j  = j0 + c;
    hold  = hbuf0[(j >> 2) * 128 + (pb << 2) + (j & 3)];
    inh_r = inhib[(size_t)pb * (TSTEPS * H4T) + j];   // t=0
    iv_r  = inp[pb * TSTEPS];                          // t=0
  }
  __syncthreads();

  int cur = 0;
  const float4* __restrict__ Wl4 = (const float4*)Wl;
  const int lane = tid & 63;

  for (int t = 0; t < TSTEPS; ++t) {
    const float* hb  = cur ? hbuf1 : hbuf0;
    float*       hbn = cur ? hbuf0 : hbuf1;
    const unsigned long long* __restrict__ hb8 = (const unsigned long long*)hb;

    // ---- full-burst sc1 h loads: one MALL round-trip for the whole slice ----
    unsigned long long p[SLICE4][2];
#pragma unroll
    for (int k = 0; k < SLICE4; ++k) {
      int fi4 = jl * SLICE4 + k;
      int i4  = (MAP == 0) ? ibase4 + fi4
              : (MAP == 1) ? ((fi4 >= 128) ? fi4 + 128 : fi4)
                           : ((fi4 >= 128) ? fi4 + 256 : fi4);
      const unsigned long long* hp = hb8 + (size_t)(i4 * 32 + b) * 2;
      p[k][0] = __hip_atomic_load(hp,     __ATOMIC_RELAXED, __HIP_MEMORY_SCOPE_AGENT);
      p[k][1] = __hip_atomic_load(hp + 1, __ATOMIC_RELAXED, __HIP_MEMORY_SCOPE_AGENT);
    }

    // ---- packed-FMA dot products (v_pk_fma_f32) ----
    f2 acc2[NCOLS];
#pragma unroll
    for (int c = 0; c < NCOLS; ++c) acc2[c] = (f2){0.0f, 0.0f};

#pragma unroll
    for (int k = 0; k < SLICE4; ++k) {
      int fi4 = jl * SLICE4 + k;
      f2 h0 = __builtin_bit_cast(f2, p[k][0]);
      f2 h1 = __builtin_bit_cast(f2, p[k][1]);
#pragma unroll
      for (int c = 0; c < NCOLS; ++c) {
        float4 wv = Wl4[c * IEXT4 + fi4];
        f2 w0 = {wv.x, wv.y};
        f2 w1 = {wv.z, wv.w};
        acc2[c] = __builtin_elementwise_fma(h0, w0, acc2[c]);
        acc2[c] = __builtin_elementwise_fma(h1, w1, acc2[c]);
      }
    }

    // ---- write partials: red[jl][c][b], b consecutive -> conflict-free ----
#pragma unroll
    for (int c = 0; c < NCOLS; ++c)
      red[(jl * NCOLS + c) * 33 + b] = acc2[c].x + acc2[c].y;
    __syncthreads();

    // ---- reduce + pointwise update + stores ----
    if (tid < 32 * NCOLS) {
      int c  = tid & (NCOLS - 1);
      int pb = tid >> LOG2NC;
      float s = 0.0f;
#pragma unroll
      for (int sl = 0; sl < NSLICE; ++sl)
        s += red[(sl * NCOLS + c) * 33 + pb];
      int j = j0 + c;
      float d    = inh_r + tonicv + iv_r * iwl[c];
      float hnew = fmaxf(0.0f, fmaf(0.01f, s + d - hold, hold));
      hold = hnew;
      // sc1 store: lands at MALL, nothing dirty in L2 for h
      __hip_atomic_store(&hbn[(j >> 2) * 128 + (pb << 2) + (j & 3)], hnew,
                         __ATOMIC_RELAXED, __HIP_MEMORY_SCOPE_AGENT);
      out_rnn[(size_t)pb * (TSTEPS * H4T) + (size_t)t * H4T + j] = hnew;
      if (t == TSTEPS - 1) out_hn[pb * H4T + j] = hnew;
    }
    __syncthreads();   // per-wave vmcnt(0) before s_barrier: all h stores MALL-acked

    // ---- arrival flag, then prefetch t+1 drive (hides under barrier wait) ----
    if (tid == 0)
      __hip_atomic_store(&arr[t * NBLK + bid], 1u,
                         __ATOMIC_RELAXED, __HIP_MEMORY_SCOPE_AGENT);
    if (tid < 32 * NCOLS) {
      int c  = tid & (NCOLS - 1);
      int pb = tid >> LOG2NC;
      int tn = (t + 1 < TSTEPS) ? t + 1 : t;
      inh_r = inhib[(size_t)pb * (TSTEPS * H4T) + (size_t)tn * H4T + (j0 + c)];
      iv_r  = inp[pb * TSTEPS + tn];
    }

    // ---- flat barrier: every wave polls all 256 flags independently ----
    {
      const unsigned long long* fp = (const unsigned long long*)(arr + t * NBLK);
      const unsigned long long want = 0x0000000100000001ULL;
      for (;;) {
        unsigned long long a0 = __hip_atomic_load(fp + lane,
                                  __ATOMIC_RELAXED, __HIP_MEMORY_SCOPE_AGENT);
        unsigned long long a1 = __hip_atomic_load(fp + 64 + lane,
                                  __ATOMIC_RELAXED, __HIP_MEMORY_SCOPE_AGENT);
        if (__all(a0 == want && a1 == want)) break;
        __builtin_amdgcn_s_sleep(1);
      }
    }
    cur ^= 1;
  }
}

__global__ __launch_bounds__(NTHR) void rnn_persistent(
    const float* __restrict__ inp, const float* __restrict__ inhib,
    const float* s2s_f, const float* t2s, const float* a2s,
    const float* s2n, const float* n2t, const float* t2a, const float* a2a,
    const float* __restrict__ inpw,
    float* __restrict__ out_hn, float* __restrict__ out_rnn,
    float* hbuf0, float* hbuf1, unsigned int* arr)
{
  __shared__ __align__(16) float Wl[8192];    // W slice, persistent across steps
  __shared__ float red[8448];                 // [NSLICE][NCOLS][33] partials
  __shared__ float iwl[16];

  int bid = blockIdx.x;
  if (bid < 64) {
    // str rows j0<256: thal2str block is all-zero -> extent 1024
    run_group<4, 1024, 2, 2>(0, bid * 4, 0, 0.0f,
        inp, inhib, s2s_f, t2s, a2s, s2n, n2t, t2a, a2a, inpw,
        out_hn, out_rnn, hbuf0, hbuf1, arr, Wl, red, iwl);
  } else if (bid < 128) {
    run_group<4, 1536, 1, 2>(0, bid * 4, 0, 0.0f,
        inp, inhib, s2s_f, t2s, a2s, s2n, n2t, t2a, a2a, inpw,
        out_hn, out_rnn, hbuf0, hbuf1, arr, Wl, red, iwl);
  } else if (bid < 160) {
    run_group<16, 512, 0, 4>(1, 512 + (bid - 128) * 16, 0, 0.7f,
        inp, inhib, s2s_f, t2s, a2s, s2n, n2t, t2a, a2a, inpw,
        out_hn, out_rnn, hbuf0, hbuf1, arr, Wl, red, iwl);
  } else if (bid < 192) {
    run_group<16, 512, 0, 4>(2, 1024 + (bid - 160) * 16, 128, 1.0f,
        inp, inhib, s2s_f, t2s, a2s, s2n, n2t, t2a, a2a, inpw,
        out_hn, out_rnn, hbuf0, hbuf1, arr, Wl, red, iwl);
  } else {
    run_group<8, 1024, 0, 3>(3, 1536 + (bid - 192) * 8, 256, 0.0f,
        inp, inhib, s2s_f, t2s, a2s, s2n, n2t, t2a, a2a, inpw,
        out_hn, out_rnn, hbuf0, hbuf1, arr, Wl, red, iwl);
  }
}

extern "C" void kernel_launch(void* const* d_in, const int* in_sizes, int n_in,
                              void* d_out, int out_size, void* d_ws, size_t ws_size,
                              hipStream_t stream) {
  const float* inp   = (const float*)d_in[0];   // [32,1000,1]
  const float* hn    = (const float*)d_in[1];   // [1,32,2048]
  const float* inhib = (const float*)d_in[2];   // [32,1000,2048]
  // d_in[3] = str2str_w (multiplied by 0.0 in reference -> unused)
  const float* t2a   = (const float*)d_in[4];   // thal2alm_w
  const float* t2s   = (const float*)d_in[5];   // thal2str_w
  const float* a2a   = (const float*)d_in[6];   // alm2alm_w
  const float* a2s   = (const float*)d_in[7];   // alm2str_w
  const float* s2n   = (const float*)d_in[8];   // str2snr_w
  const float* n2t   = (const float*)d_in[9];   // snr2thal_w
  const float* inpw  = (const float*)d_in[10];  // inp_weight [1,2048]
  const float* s2s_f = (const float*)d_in[11];  // str2str_fixed

  float* out_hn  = (float*)d_out;               // [1,32,2048]
  float* out_rnn = out_hn + BATCHN * H4T;       // [32,1000,2048]

  float* hbuf0 = (float*)d_ws;
  float* hbuf1 = hbuf0 + BATCHN * H4T;
  unsigned int* arr = (unsigned int*)((char*)d_ws + 512 * 1024);

  // zero arrival flags (1000*256*4 = 1MB), once per call
  hipMemsetAsync(arr, 0, TSTEPS * NBLK * sizeof(unsigned int), stream);
  prep_h0<<<256, 256, 0, stream>>>(hn, hbuf0);
  rnn_persistent<<<NBLK, NTHR, 0, stream>>>(
      inp, inhib, s2s_f, t2s, a2s, s2n, n2t, t2a, a2a, inpw,
      out_hn, out_rnn, hbuf0, hbuf1, arr);
}